// Round 16
// baseline (137.888 us; speedup 1.0000x reference)
//
#include <hip/hip_runtime.h>
#include <hip/hip_bf16.h>

// ---------------- constants ----------------
#define F 128           // hidden width
#define NHID 7          // hidden 128->128 layers
#define BP 80           // points per MLP block (250 blocks exactly, <=1/CU)
#define NPT 5           // ptiles per wave
#define TRUNC_ 2.0f

// spatial grid: cell size must be >= sqrt(2) (truncation radius)
#define GM 32                  // cells per dimension
#define GM3 (GM * GM * GM)     // 32768
#define GLO (-28.0f)
#define CELL 1.75f
#define GINV (1.0f / 1.75f)
#define SCAN_BLKS (GM3 / 256)  // 128 scan blocks per grid
#define NGRID 4
#define NDIR 2                 // direction PAIRS (symmetric scatter covers reverse)
#define PACKB 112              // pack blocks (8 elems/thread)
#define ZCB 128                // count-zero blocks (int4)
#define QMB 40                 // qmin-init blocks (uint4, 40960 uints)
#define ZB (NGRID * GM3 / 256) // 512 scan blocks
#define BQ 128                 // queries per search block (2 threads/query)

typedef __attribute__((ext_vector_type(8))) short short8v;
typedef __attribute__((ext_vector_type(4))) float f32x4;

__device__ inline unsigned short f2bf(float v)
{
    __hip_bfloat16 b = __float2bfloat16(v);
    return __builtin_bit_cast(unsigned short, b);
}
__device__ inline float bf2f(unsigned short u)
{
    unsigned int x = ((unsigned int)u) << 16;
    return __builtin_bit_cast(float, x);
}

// h LDS layout: [80 rows][128 ushorts], 16B-unit XOR-swizzled by row&7.
__device__ inline int hsw(int row, int col)   // col in ushorts
{
    return row * 128 + ((((col >> 3) ^ (row & 7)) << 3) | (col & 7));
}

// barrier WITHOUT vmcnt drain: LDS writes visible, global prefetches stay in flight
__device__ inline void barrier_nd()
{
    asm volatile("s_waitcnt lgkmcnt(0)" ::: "memory");
    __builtin_amdgcn_s_barrier();
}

// ---------------- prep: pack W^T A-frags (bf16), WlT, zero counts+done, init qmins ----------------
__global__ __launch_bounds__(256) void prep_kernel(
    const float* __restrict__ Wh, const float* __restrict__ Whi,
    const float* __restrict__ Wl, const float* __restrict__ Wli,
    unsigned short* __restrict__ whp,
    float* __restrict__ wlt, int* __restrict__ counts,
    unsigned int* __restrict__ done, unsigned int* __restrict__ qmins)
{
    int bid = blockIdx.x;
    int t = threadIdx.x;
    if (bid < PACKB) {
        int g = bid * 256 + t;               // tuple id: 14*4*8*64 = 28672 exactly
        int l = g & 63;
        int tt = (g >> 6) & 7;
        int s = (g >> 9) & 3;
        int m = g >> 11;                     // 0..13 : mlp*7 + layer
        int k0 = s * 32 + (l >> 4) * 8;
        int c = tt * 16 + (l & 15);
        const float* W = (m < 7 ? Wh + (size_t)m * F * F
                                : Whi + (size_t)(m - 7) * F * F);
        short8v v;
#pragma unroll
        for (int j = 0; j < 8; ++j)
            v[j] = (short)f2bf(W[(k0 + j) * F + c]);
        *(short8v*)(whp + (size_t)g * 8) = v;
    } else if (bid < PACKB + ZCB) {
        *(int4*)&counts[((bid - PACKB) * 256 + t) * 4] = make_int4(0, 0, 0, 0);
    } else if (bid == PACKB + ZCB) {
        // WlT[mlp][c][k] = Wl[k*3+c], 2*3*128 = 768 floats
#pragma unroll
        for (int r = 0; r < 3; ++r) {
            int e = r * 256 + t;
            int mI = e / 384;
            int rem = e - mI * 384;
            int c = rem >> 7;
            int k = rem & 127;
            const float* W = mI ? Wli : Wl;
            wlt[e] = W[k * 3 + c];
        }
        if (t == 0) *done = 0u;
    } else {
        // init qmins (2 target clouds, padded to 40960) to +inf bits
        const unsigned int inf = 0x7f7fffffu;
        uint4 v = make_uint4(inf, inf, inf, inf);
        *(uint4*)&qmins[((bid - PACKB - ZCB - 1) * 256 + t) * 4] = v;
    }
}

// ---------------- spatial grid cell ----------------
__device__ inline int cell_of(float x, float y, float z)
{
    int cx = (int)floorf((x - GLO) * GINV);
    int cy = (int)floorf((y - GLO) * GINV);
    int cz = (int)floorf((z - GLO) * GINV);
    cx = min(max(cx, 0), GM - 1);
    cy = min(max(cy, 0), GM - 1);
    cz = min(max(cz, 0), GM - 1);
    return (cz * GM + cy) * GM + cx;
}

// ---------------- fused double-MLP via MFMA + grid counting epilogue ----------------
// (r13-verified structure: wave = 1 mtile x 5 ptiles, bf16 W, x-layer prefetch)
__global__ __launch_bounds__(512, 2) void mlp_fused_kernel(
    const float* __restrict__ pc0, const float* __restrict__ pc1,
    const float* __restrict__ W0a, const float* __restrict__ b0a,
    const float* __restrict__ W0b, const float* __restrict__ b0b,
    const unsigned short* __restrict__ whp,  // packed W^T A-frags bf16, 14 layers
    const float* __restrict__ bha, const float* __restrict__ bhb,
    const float* __restrict__ wlt,           // WlT [2][3][128]
    const float* __restrict__ bla, const float* __restrict__ blb,
    float* __restrict__ Aout, float* __restrict__ Cout,
    int* __restrict__ counts, int N)
{
    __shared__ unsigned short hX[BP * 128];
    __shared__ unsigned short hY[BP * 128];
    __shared__ float Al[BP][4];
    __shared__ float Cl[BP][4];

    const int tid = threadIdx.x;
    const int lane = tid & 63;
    const int wv = tid >> 6;          // 0..7 == mtile
    const int arow = lane & 15;       // A row (f_out) / B col (point)
    const int kg = lane >> 4;         // k-group / C row-group
    const int p0 = blockIdx.x * BP;

    unsigned short* cur = hX;
    unsigned short* nxt = hY;

    short8v wA, wB;
    short8v hA[NPT], hB[NPT];

#define LW(WD, LI, S) { \
        size_t off = ((size_t)(((LI) * 4 + (S)) * 8 + wv) * 64 + lane) * 8; \
        WD = *(const short8v*)(whp + off); }
#define LH(D, S) { _Pragma("unroll") for (int p = 0; p < NPT; ++p) \
        D[p] = *(const short8v*)&cur[hsw(p * 16 + arow, (S) * 32 + kg * 8)]; }
#define MM(WD, H) { \
    _Pragma("unroll") for (int p = 0; p < NPT; ++p) \
        acc[p] = __builtin_amdgcn_mfma_f32_16x16x32_bf16(WD, H[p], acc[p], 0, 0, 0); }

    // preload layer 0's s0/s1 weight frags (hide under layer-0 VALU)
    LW(wA, 0, 0)
    LW(wB, 0, 1)
    __builtin_amdgcn_sched_barrier(0);

    for (int M = 0; M < 2; ++M) {
        const float* W0 = M ? W0b : W0a;
        const float* b0 = M ? b0b : b0a;
        const float* bh = M ? bhb : bha;
        const float* bl = M ? blb : bla;

        // ---- layer 0 (3->128) on VALU: 512 threads, 5 pts each ----
        {
            const int jg = tid & 31;
            const int pgg = tid >> 5;     // 0..15 -> pts pgg*5..+5
            const int j0 = jg * 4;
            float4 wr0 = *(const float4*)(W0 + 0 * F + j0);
            float4 wr1 = *(const float4*)(W0 + 1 * F + j0);
            float4 wr2 = *(const float4*)(W0 + 2 * F + j0);
            float4 bb0 = *(const float4*)(b0 + j0);
#pragma unroll
            for (int p = 0; p < 5; ++p) {
                int pt = pgg * 5 + p;
                float x0, x1, x2;
                if (M == 0) {
                    int gp = p0 + pt;
                    int cp = gp < N ? gp : N - 1;
                    x0 = pc0[cp * 3 + 0]; x1 = pc0[cp * 3 + 1]; x2 = pc0[cp * 3 + 2];
                } else {
                    x0 = Al[pt][0]; x1 = Al[pt][1]; x2 = Al[pt][2];
                }
                float hx = fmaxf(fmaf(x0, wr0.x, fmaf(x1, wr1.x, fmaf(x2, wr2.x, bb0.x))), 0.f);
                float hy = fmaxf(fmaf(x0, wr0.y, fmaf(x1, wr1.y, fmaf(x2, wr2.y, bb0.y))), 0.f);
                float hz = fmaxf(fmaf(x0, wr0.z, fmaf(x1, wr1.z, fmaf(x2, wr2.z, bb0.z))), 0.f);
                float hw = fmaxf(fmaf(x0, wr0.w, fmaf(x1, wr1.w, fmaf(x2, wr2.w, bb0.w))), 0.f);
                short4 hv = make_short4((short)f2bf(hx), (short)f2bf(hy),
                                        (short)f2bf(hz), (short)f2bf(hw));
                *(short4*)&cur[hsw(pt, j0)] = hv;
            }
        }
        barrier_nd();

        // ---- 7 hidden layers, W bf16 x H bf16, 2-stage ping-pong + x-layer prefetch ----
        for (int l = 0; l < NHID; ++l) {
            const int L = M * 7 + l;
            const int Ln = (L + 1 < 14) ? (L + 1) : 13;
            f32x4 acc[NPT];
            {
                float4 b4 = *(const float4*)&bh[l * F + wv * 16 + kg * 4];
#pragma unroll
                for (int p = 0; p < NPT; ++p)
                    acc[p] = (f32x4){b4.x, b4.y, b4.z, b4.w};
            }

            LH(hA, 0) LH(hB, 1)
            __builtin_amdgcn_sched_barrier(0);
            MM(wA, hA)                      // s0
            LW(wA, L, 2) LH(hA, 2)
            __builtin_amdgcn_sched_barrier(0);
            MM(wB, hB)                      // s1
            LW(wB, L, 3) LH(hB, 3)
            __builtin_amdgcn_sched_barrier(0);
            MM(wA, hA)                      // s2
            LW(wA, Ln, 0)                   // prefetch next layer s0
            __builtin_amdgcn_sched_barrier(0);
            MM(wB, hB)                      // s3
            LW(wB, Ln, 1)                   // prefetch next layer s1

            // ReLU + bf16 + swizzled write
#pragma unroll
            for (int p = 0; p < NPT; ++p) {
                float v0 = fmaxf(acc[p][0], 0.f), v1 = fmaxf(acc[p][1], 0.f);
                float v2 = fmaxf(acc[p][2], 0.f), v3 = fmaxf(acc[p][3], 0.f);
                short4 hv = make_short4((short)f2bf(v0), (short)f2bf(v1),
                                        (short)f2bf(v2), (short)f2bf(v3));
                *(short4*)&nxt[hsw(p * 16 + arow, wv * 16 + kg * 4)] = hv;
            }
            barrier_nd();
            unsigned short* tsw = cur; cur = nxt; nxt = tsw;
        }

        // ---- final layer 128->3: 240 threads, full-k, 4 rotating accs ----
        if (tid < 240) {
            int pt = tid / 3;
            int c = tid - 3 * pt;
            const float* wl = wlt + M * 384 + c * 128;
            float a0 = 0.f, a1 = 0.f, a2 = 0.f, a3 = 0.f;
#pragma unroll
            for (int q = 0; q < 16; ++q) {
                short8v h8 = *(const short8v*)&cur[hsw(pt, q * 8)];
                float4 wa = *(const float4*)(wl + q * 8);
                float4 wb = *(const float4*)(wl + q * 8 + 4);
                a0 = fmaf(bf2f((unsigned short)h8[0]), wa.x, a0);
                a1 = fmaf(bf2f((unsigned short)h8[1]), wa.y, a1);
                a2 = fmaf(bf2f((unsigned short)h8[2]), wa.z, a2);
                a3 = fmaf(bf2f((unsigned short)h8[3]), wa.w, a3);
                a0 = fmaf(bf2f((unsigned short)h8[4]), wb.x, a0);
                a1 = fmaf(bf2f((unsigned short)h8[5]), wb.y, a1);
                a2 = fmaf(bf2f((unsigned short)h8[6]), wb.z, a2);
                a3 = fmaf(bf2f((unsigned short)h8[7]), wb.w, a3);
            }
            float flow = ((a0 + a1) + (a2 + a3)) + bl[c];
            int gp = p0 + pt;
            int cp = gp < N ? gp : N - 1;
            if (M == 0) {
                float val = pc0[cp * 3 + c] + flow;
                Al[pt][c] = val;
                if (gp < N) Aout[gp * 3 + c] = val;
            } else {
                float val = Al[pt][c] - flow;
                Cl[pt][c] = val;
                if (gp < N) Cout[gp * 3 + c] = val;
            }
        }
        barrier_nd();
    }
#undef LW
#undef LH
#undef MM

    // ---- epilogue: grid counts for all 4 clouds (block's own points) ----
    if (tid < BP) {
        int gp = p0 + tid;
        if (gp < N) {
            atomicAdd(&counts[1 * GM3 + cell_of(Al[tid][0], Al[tid][1], Al[tid][2])], 1);
            atomicAdd(&counts[3 * GM3 + cell_of(Cl[tid][0], Cl[tid][1], Cl[tid][2])], 1);
            atomicAdd(&counts[0 * GM3 + cell_of(pc1[gp * 3 + 0], pc1[gp * 3 + 1], pc1[gp * 3 + 2])], 1);
            atomicAdd(&counts[2 * GM3 + cell_of(pc0[gp * 3 + 0], pc0[gp * 3 + 1], pc0[gp * 3 + 2])], 1);
        }
    }
}

// ---------------- grid build ----------------
__device__ inline const float* cloud_ptr(int g, const float* g0, const float* g1,
                                         const float* g2, const float* g3)
{
    return g == 0 ? g0 : (g == 1 ? g1 : (g == 2 ? g2 : g3));
}

__global__ __launch_bounds__(256) void scan1(
    const int* __restrict__ counts, int* __restrict__ offs, int* __restrict__ bsum)
{
    int tid = threadIdx.x;
    int i = blockIdx.x * 256 + tid;
    int v = counts[i];
    __shared__ int s[256];
    s[tid] = v;
    __syncthreads();
#pragma unroll
    for (int off = 1; off < 256; off <<= 1) {
        int t = (tid >= off) ? s[tid - off] : 0;
        __syncthreads();
        s[tid] += t;
        __syncthreads();
    }
    offs[i] = s[tid] - v;           // exclusive
    if (tid == 255) bsum[blockIdx.x] = s[255];
}

// scan2+scan3 fused: per-block segment prefix of bsum (SCAN_BLKS=128 <= 256),
// add to offs, re-zero counts (cursors for grid_fill)
__global__ __launch_bounds__(256) void scan23(
    int* __restrict__ offs, const int* __restrict__ bsum, int* __restrict__ counts)
{
    int seg = blockIdx.x / SCAN_BLKS;
    int pos = blockIdx.x - seg * SCAN_BLKS;
    const int* bs = bsum + seg * SCAN_BLKS;
    int t = threadIdx.x;
    int v = (t < pos) ? bs[t] : 0;
    __shared__ int red[4];
#pragma unroll
    for (int o = 32; o > 0; o >>= 1) v += __shfl_down(v, o, 64);
    if ((t & 63) == 0) red[t >> 6] = v;
    __syncthreads();
    int prefix = red[0] + red[1] + red[2] + red[3];
    int i = blockIdx.x * 256 + t;
    offs[i] += prefix;
    counts[i] = 0;
}

__global__ __launch_bounds__(256) void grid_fill(
    const float* __restrict__ B, const float* __restrict__ A,
    const float* __restrict__ D, const float* __restrict__ C,
    const int* __restrict__ offs, int* __restrict__ counts,
    float4* __restrict__ pts, int n)
{
    int g = blockIdx.y;
    const float* P = cloud_ptr(g, B, A, D, C);
    int i = blockIdx.x * 256 + threadIdx.x;
    if (i < n) {
        float x = P[i * 3 + 0], y = P[i * 3 + 1], z = P[i * 3 + 2];
        int c = g * GM3 + cell_of(x, y, z);
        int slot = offs[c] + atomicAdd(&counts[c], 1);
        pts[(size_t)g * n + slot] = make_float4(x, y, z, 0.f);
    }
}

// ---------------- block sum helper ----------------
__device__ inline float block_sum256(float v)
{
    __shared__ float sws[4];
#pragma unroll
    for (int o = 32; o > 0; o >>= 1) v += __shfl_down(v, o, 64);
    int w = threadIdx.x >> 6;
    if ((threadIdx.x & 63) == 0) sws[w] = v;
    __syncthreads();
    if (threadIdx.x == 0) v = sws[0] + sws[1] + sws[2] + sws[3];
    return v;
}

// 1-D box distance from q to cell index c (cell spans [GLO+c*CELL, GLO+(c+1)*CELL])
__device__ inline float boxd1(float q, int c)
{
    float lo = GLO + c * CELL;
    return fmaxf(fmaxf(lo - q, q - (lo + CELL)), 0.f);
}

// symmetric truncated NN search: 2 direction PAIRS. Queries = sorted cloud
// gq = 2d+1 (A or C); targets = sorted cloud gt = 2d (pc1 or pc0). Per-query
// min accumulated in-register (forward term); per-TARGET min accumulated by
// atomicMin scatter on uint-encoded d^2 (reverse term) -- every pair with
// d^2 < TRUNC is enumerated by the forward pass (cell size >= sqrt(TRUNC)),
// so the reverse mins are exact; targets never hit stay +inf -> truncate to 0.
// 2 threads per query (rows 0-3 / 4-8); block sum + fused final reduce.
__global__ __launch_bounds__(256) void grid_search(
    const int* __restrict__ offs, const int* __restrict__ counts,
    const float4* __restrict__ pts, float* __restrict__ partials,
    unsigned int* __restrict__ qmins,
    unsigned int* __restrict__ done, float* __restrict__ out, float inv, int n)
{
    const int d = blockIdx.y;               // 0: A->pc1 ; 1: C->pc0
    const int gq = 2 * d + 1, gt = 2 * d;
    const float4* Qs = pts + (size_t)gq * n;
    const float4* P  = pts + (size_t)gt * n;
    const int* ofs = offs + (size_t)gt * GM3;
    const int* cnt = counts + (size_t)gt * GM3;
    unsigned int* qm = qmins + (size_t)d * n;

    const int tid = threadIdx.x;
    const int ql = tid & (BQ - 1);
    const int half = tid >> 7;          // 0: rows 0-3, 1: rows 4-8
    const int i = blockIdx.x * BQ + ql;

    float mn = 3.4e38f;
    if (i < n) {
        float4 q = Qs[i];
        int cx = min(max((int)floorf((q.x - GLO) * GINV), 0), GM - 1);
        int cy = min(max((int)floorf((q.y - GLO) * GINV), 0), GM - 1);
        int cz = min(max((int)floorf((q.z - GLO) * GINV), 0), GM - 1);
        int xcl = max(cx - 1, 0), xch = min(cx + 1, GM - 1);
        int r0 = half * 4;

        int o[5], e[5];
#pragma unroll
        for (int r = 0; r < 5; ++r) {
            o[r] = 0; e[r] = 0;
            bool act = half ? true : (r < 4);
            if (act) {
                int rr = r0 + r;                 // 0..3 or 4..8
                int dz = rr / 3, dy = rr - dz * 3;
                int z = cz + dz - 1;
                int y = cy + dy - 1;
                if ((unsigned)z < GM && (unsigned)y < GM) {
                    float dzd = boxd1(q.z, z);
                    float dyd = boxd1(q.y, y);
                    float dyz2 = fmaf(dzd, dzd, dyd * dyd);
                    if (dyz2 < TRUNC_) {
                        float rx = sqrtf(TRUNC_ - dyz2);
                        int xlo = max((int)floorf((q.x - rx - GLO) * GINV), xcl);
                        int xhi = min((int)floorf((q.x + rx - GLO) * GINV), xch);
                        if (xlo <= xhi) {
                            int rowbase = (z * GM + y) * GM;
                            o[r] = ofs[rowbase + xlo];
                            e[r] = ofs[rowbase + xhi] + cnt[rowbase + xhi];
                        }
                    }
                }
            }
        }
#pragma unroll
        for (int r = 0; r < 5; ++r) {
            for (int k = o[r]; k < e[r]; ++k) {
                float4 p = P[k];
                float ddx = q.x - p.x, ddy = q.y - p.y, ddz = q.z - p.z;
                float dd = fmaf(ddx, ddx, fmaf(ddy, ddy, ddz * ddz));
                mn = fminf(mn, dd);
                if (dd < TRUNC_)
                    atomicMin(&qm[k], __float_as_uint(dd));   // reverse-direction min
            }
        }
    }

    __shared__ float m0[BQ];
    if (half == 0) m0[ql] = mn;
    __syncthreads();
    float val = 0.f;
    if (half == 1 && i < n) {
        float m = fminf(mn, m0[ql]);
        val = (m < TRUNC_) ? m : 0.f;
    }
    float bs = block_sum256(val);

    __shared__ int lastflag;
    if (tid == 0) {
        atomicExch(&partials[(size_t)d * gridDim.x + blockIdx.x], bs);
        __threadfence();
        unsigned v = atomicAdd(done, 1u);
        lastflag = (v == (unsigned)(NDIR * gridDim.x - 1)) ? 1 : 0;
    }
    __syncthreads();
    if (lastflag) {
        int NPt = NDIR * gridDim.x;
        float s = 0.f;
        for (int j = tid; j < NPt; j += 256)
            s += atomicAdd(&partials[j], 0.0f);   // device-scope read
        // reverse-direction sums from qmin arrays (device-scope reads)
        for (int j = tid; j < 2 * n; j += 256) {
            unsigned u = atomicAdd(&qmins[j], 0u);
            float m = __uint_as_float(u);
            s += (m < TRUNC_) ? m : 0.f;
        }
        __syncthreads();
        float tot = block_sum256(s);
        if (tid == 0) out[0] = tot * inv;
    }
}

// ---------------- launch ----------------
extern "C" void kernel_launch(void* const* d_in, const int* in_sizes, int n_in,
                              void* d_out, int out_size, void* d_ws, size_t ws_size,
                              hipStream_t stream)
{
    const float* pc0 = (const float*)d_in[0];
    const float* pc1 = (const float*)d_in[1];
    const float* W0  = (const float*)d_in[2];
    const float* b0  = (const float*)d_in[3];
    const float* Wh  = (const float*)d_in[4];
    const float* bh  = (const float*)d_in[5];
    const float* Wl  = (const float*)d_in[6];
    const float* bl  = (const float*)d_in[7];
    const float* W0i = (const float*)d_in[8];
    const float* b0i = (const float*)d_in[9];
    const float* Whi = (const float*)d_in[10];
    const float* bhi = (const float*)d_in[11];
    const float* Wli = (const float*)d_in[12];
    const float* bli = (const float*)d_in[13];
    float* out = (float*)d_out;

    const int N = in_sizes[0] / 3;   // 20000

    // ws layout (byte offsets)
    char* base = (char*)d_ws;
    float*  A        = (float*)(base + 0);               // 240000
    float*  C        = (float*)(base + 240000);          // 240000
    int*    counts   = (int*)  (base + 480000);          // 524288
    int*    offs     = (int*)  (base + 1004288);         // 524288
    int*    bsum     = (int*)  (base + 1528576);         // 4096
    float4* pts      = (float4*)(base + 1532672);        // 1280000
    float*  partials = (float*)(base + 2812672);         // 4096
    unsigned int* done = (unsigned int*)(base + 2816768);// 16
    unsigned short* whp = (unsigned short*)(base + 2816784); // 458752
    float*  wlt      = (float*)(base + 3275536);         // 3072
    unsigned int* qmins = (unsigned int*)(base + 3278608);   // 163840 (40960 uints)

    const int PB = (N + 255) / 256;        // 79
    const int QB = (N + BQ - 1) / BQ;      // 157 search blocks per direction pair

    // prep: pack weights (bf16) + WlT + zero counts + done + init qmins
    hipLaunchKernelGGL(prep_kernel, dim3(PACKB + ZCB + 1 + QMB), dim3(256), 0, stream,
                       Wh, Whi, Wl, Wli, whp, wlt, counts, done, qmins);

    int mlpg = (N + BP - 1) / BP;  // 250
    hipLaunchKernelGGL(mlp_fused_kernel, dim3(mlpg), dim3(512), 0, stream,
                       pc0, pc1, W0, b0, W0i, b0i, whp, bh, bhi,
                       wlt, bl, bli, A, C, counts, N);

    // grids: g0=pc1, g1=A, g2=pc0, g3=C (counts already done in mlp epilogue)
    hipLaunchKernelGGL(scan1, dim3(ZB), dim3(256), 0, stream, counts, offs, bsum);
    hipLaunchKernelGGL(scan23, dim3(ZB), dim3(256), 0, stream, offs, bsum, counts);
    hipLaunchKernelGGL(grid_fill, dim3(PB, NGRID), dim3(256), 0, stream,
                       pc1, A, pc0, C, offs, counts, pts, N);

    // symmetric sphere-culled search (2 direction pairs) + fused final reduce
    hipLaunchKernelGGL(grid_search, dim3(QB, NDIR), dim3(256), 0, stream,
                       offs, counts, pts, partials, qmins, done, out,
                       1.0f / (float)N, N);
}

// Round 17
// 76.586 us; speedup vs baseline: 1.8004x; 1.8004x over previous
//
#include <hip/hip_runtime.h>
#include <hip/hip_bf16.h>

// ---------------- constants ----------------
#define F 128           // hidden width
#define NHID 7          // hidden 128->128 layers
#define BP 80           // points per MLP block (250 blocks exactly, <=1/CU)
#define NPT 5           // ptiles per wave
#define TRUNC_ 2.0f

// spatial grid: cell size must be >= sqrt(2) (truncation radius)
#define GM 32                  // cells per dimension
#define GM3 (GM * GM * GM)     // 32768
#define GLO (-28.0f)
#define CELL 1.75f
#define GINV (1.0f / 1.75f)
#define SCAN_BLKS (GM3 / 256)  // 128 scan blocks per grid
#define NGRID 4
#define PACKB 112              // pack blocks (8 elems/thread)
#define ZCB 128                // count-zero blocks (int4)
#define ZB (NGRID * GM3 / 256) // 512 scan blocks
#define BQ 128                 // queries per search block (2 threads/query)

typedef __attribute__((ext_vector_type(8))) short short8v;
typedef __attribute__((ext_vector_type(4))) float f32x4;

__device__ inline unsigned short f2bf(float v)
{
    __hip_bfloat16 b = __float2bfloat16(v);
    return __builtin_bit_cast(unsigned short, b);
}
__device__ inline float bf2f(unsigned short u)
{
    unsigned int x = ((unsigned int)u) << 16;
    return __builtin_bit_cast(float, x);
}

// h LDS layout: [80 rows][128 ushorts], 16B-unit XOR-swizzled by row&7.
__device__ inline int hsw(int row, int col)   // col in ushorts
{
    return row * 128 + ((((col >> 3) ^ (row & 7)) << 3) | (col & 7));
}

// barrier WITHOUT vmcnt drain: LDS writes visible, global prefetches stay in flight
__device__ inline void barrier_nd()
{
    asm volatile("s_waitcnt lgkmcnt(0)" ::: "memory");
    __builtin_amdgcn_s_barrier();
}

// ---------------- prep: pack W^T A-frags (bf16), WlT, zero counts+done ----------------
__global__ __launch_bounds__(256) void prep_kernel(
    const float* __restrict__ Wh, const float* __restrict__ Whi,
    const float* __restrict__ Wl, const float* __restrict__ Wli,
    unsigned short* __restrict__ whp,
    float* __restrict__ wlt, int* __restrict__ counts, unsigned int* __restrict__ done)
{
    int bid = blockIdx.x;
    int t = threadIdx.x;
    if (bid < PACKB) {
        int g = bid * 256 + t;               // tuple id: 14*4*8*64 = 28672 exactly
        int l = g & 63;
        int tt = (g >> 6) & 7;
        int s = (g >> 9) & 3;
        int m = g >> 11;                     // 0..13 : mlp*7 + layer
        int k0 = s * 32 + (l >> 4) * 8;
        int c = tt * 16 + (l & 15);
        const float* W = (m < 7 ? Wh + (size_t)m * F * F
                                : Whi + (size_t)(m - 7) * F * F);
        short8v v;
#pragma unroll
        for (int j = 0; j < 8; ++j)
            v[j] = (short)f2bf(W[(k0 + j) * F + c]);
        *(short8v*)(whp + (size_t)g * 8) = v;
    } else if (bid < PACKB + ZCB) {
        *(int4*)&counts[((bid - PACKB) * 256 + t) * 4] = make_int4(0, 0, 0, 0);
    } else {
        // WlT[mlp][c][k] = Wl[k*3+c], 2*3*128 = 768 floats
#pragma unroll
        for (int r = 0; r < 3; ++r) {
            int e = r * 256 + t;
            int mI = e / 384;
            int rem = e - mI * 384;
            int c = rem >> 7;
            int k = rem & 127;
            const float* W = mI ? Wli : Wl;
            wlt[e] = W[k * 3 + c];
        }
        if (t == 0) *done = 0u;
    }
}

// ---------------- spatial grid cell ----------------
__device__ inline int cell_of(float x, float y, float z)
{
    int cx = (int)floorf((x - GLO) * GINV);
    int cy = (int)floorf((y - GLO) * GINV);
    int cz = (int)floorf((z - GLO) * GINV);
    cx = min(max(cx, 0), GM - 1);
    cy = min(max(cy, 0), GM - 1);
    cz = min(max(cz, 0), GM - 1);
    return (cz * GM + cy) * GM + cx;
}

// ---------------- fused double-MLP via MFMA + grid counting epilogue ----------------
// A = pc0 + mlp1(pc0); C = A - mlp2(A); counts for all 4 clouds.
// 8 waves; wave wv owns mtile wv (16 f_out) x all 5 ptiles. W in plain bf16.
__global__ __launch_bounds__(512, 2) void mlp_fused_kernel(
    const float* __restrict__ pc0, const float* __restrict__ pc1,
    const float* __restrict__ W0a, const float* __restrict__ b0a,
    const float* __restrict__ W0b, const float* __restrict__ b0b,
    const unsigned short* __restrict__ whp,  // packed W^T A-frags bf16, 14 layers
    const float* __restrict__ bha, const float* __restrict__ bhb,
    const float* __restrict__ wlt,           // WlT [2][3][128]
    const float* __restrict__ bla, const float* __restrict__ blb,
    float* __restrict__ Aout, float* __restrict__ Cout,
    int* __restrict__ counts, int N)
{
    __shared__ unsigned short hX[BP * 128];
    __shared__ unsigned short hY[BP * 128];
    __shared__ float Al[BP][4];
    __shared__ float Cl[BP][4];

    const int tid = threadIdx.x;
    const int lane = tid & 63;
    const int wv = tid >> 6;          // 0..7 == mtile
    const int arow = lane & 15;       // A row (f_out) / B col (point)
    const int kg = lane >> 4;         // k-group / C row-group
    const int p0 = blockIdx.x * BP;

    unsigned short* cur = hX;
    unsigned short* nxt = hY;

    short8v wA, wB;
    short8v hA[NPT], hB[NPT];

#define LW(WD, LI, S) { \
        size_t off = ((size_t)(((LI) * 4 + (S)) * 8 + wv) * 64 + lane) * 8; \
        WD = *(const short8v*)(whp + off); }
#define LH(D, S) { _Pragma("unroll") for (int p = 0; p < NPT; ++p) \
        D[p] = *(const short8v*)&cur[hsw(p * 16 + arow, (S) * 32 + kg * 8)]; }
#define MM(WD, H) { \
    _Pragma("unroll") for (int p = 0; p < NPT; ++p) \
        acc[p] = __builtin_amdgcn_mfma_f32_16x16x32_bf16(WD, H[p], acc[p], 0, 0, 0); }

    // preload layer 0's s0/s1 weight frags (hide under layer-0 VALU)
    LW(wA, 0, 0)
    LW(wB, 0, 1)
    __builtin_amdgcn_sched_barrier(0);

    for (int M = 0; M < 2; ++M) {
        const float* W0 = M ? W0b : W0a;
        const float* b0 = M ? b0b : b0a;
        const float* bh = M ? bhb : bha;
        const float* bl = M ? blb : bla;

        // ---- layer 0 (3->128) on VALU: 512 threads, 5 pts each ----
        {
            const int jg = tid & 31;
            const int pgg = tid >> 5;     // 0..15 -> pts pgg*5..+5
            const int j0 = jg * 4;
            float4 wr0 = *(const float4*)(W0 + 0 * F + j0);
            float4 wr1 = *(const float4*)(W0 + 1 * F + j0);
            float4 wr2 = *(const float4*)(W0 + 2 * F + j0);
            float4 bb0 = *(const float4*)(b0 + j0);
#pragma unroll
            for (int p = 0; p < 5; ++p) {
                int pt = pgg * 5 + p;
                float x0, x1, x2;
                if (M == 0) {
                    int gp = p0 + pt;
                    int cp = gp < N ? gp : N - 1;
                    x0 = pc0[cp * 3 + 0]; x1 = pc0[cp * 3 + 1]; x2 = pc0[cp * 3 + 2];
                } else {
                    x0 = Al[pt][0]; x1 = Al[pt][1]; x2 = Al[pt][2];
                }
                float hx = fmaxf(fmaf(x0, wr0.x, fmaf(x1, wr1.x, fmaf(x2, wr2.x, bb0.x))), 0.f);
                float hy = fmaxf(fmaf(x0, wr0.y, fmaf(x1, wr1.y, fmaf(x2, wr2.y, bb0.y))), 0.f);
                float hz = fmaxf(fmaf(x0, wr0.z, fmaf(x1, wr1.z, fmaf(x2, wr2.z, bb0.z))), 0.f);
                float hw = fmaxf(fmaf(x0, wr0.w, fmaf(x1, wr1.w, fmaf(x2, wr2.w, bb0.w))), 0.f);
                short4 hv = make_short4((short)f2bf(hx), (short)f2bf(hy),
                                        (short)f2bf(hz), (short)f2bf(hw));
                *(short4*)&cur[hsw(pt, j0)] = hv;
            }
        }
        barrier_nd();

        // ---- 7 hidden layers, W bf16 x H bf16, 2-stage ping-pong + x-layer prefetch ----
        for (int l = 0; l < NHID; ++l) {
            const int L = M * 7 + l;
            const int Ln = (L + 1 < 14) ? (L + 1) : 13;
            f32x4 acc[NPT];
            {
                float4 b4 = *(const float4*)&bh[l * F + wv * 16 + kg * 4];
#pragma unroll
                for (int p = 0; p < NPT; ++p)
                    acc[p] = (f32x4){b4.x, b4.y, b4.z, b4.w};
            }

            LH(hA, 0) LH(hB, 1)
            __builtin_amdgcn_sched_barrier(0);
            MM(wA, hA)                      // s0
            LW(wA, L, 2) LH(hA, 2)
            __builtin_amdgcn_sched_barrier(0);
            MM(wB, hB)                      // s1
            LW(wB, L, 3) LH(hB, 3)
            __builtin_amdgcn_sched_barrier(0);
            MM(wA, hA)                      // s2
            LW(wA, Ln, 0)                   // prefetch next layer s0
            __builtin_amdgcn_sched_barrier(0);
            MM(wB, hB)                      // s3
            LW(wB, Ln, 1)                   // prefetch next layer s1

            // ReLU + bf16 + swizzled write
#pragma unroll
            for (int p = 0; p < NPT; ++p) {
                float v0 = fmaxf(acc[p][0], 0.f), v1 = fmaxf(acc[p][1], 0.f);
                float v2 = fmaxf(acc[p][2], 0.f), v3 = fmaxf(acc[p][3], 0.f);
                short4 hv = make_short4((short)f2bf(v0), (short)f2bf(v1),
                                        (short)f2bf(v2), (short)f2bf(v3));
                *(short4*)&nxt[hsw(p * 16 + arow, wv * 16 + kg * 4)] = hv;
            }
            barrier_nd();
            unsigned short* tsw = cur; cur = nxt; nxt = tsw;
        }

        // ---- final layer 128->3: 240 threads, full-k, 4 rotating accs ----
        if (tid < 240) {
            int pt = tid / 3;
            int c = tid - 3 * pt;
            const float* wl = wlt + M * 384 + c * 128;
            float a0 = 0.f, a1 = 0.f, a2 = 0.f, a3 = 0.f;
#pragma unroll
            for (int q = 0; q < 16; ++q) {
                short8v h8 = *(const short8v*)&cur[hsw(pt, q * 8)];
                float4 wa = *(const float4*)(wl + q * 8);
                float4 wb = *(const float4*)(wl + q * 8 + 4);
                a0 = fmaf(bf2f((unsigned short)h8[0]), wa.x, a0);
                a1 = fmaf(bf2f((unsigned short)h8[1]), wa.y, a1);
                a2 = fmaf(bf2f((unsigned short)h8[2]), wa.z, a2);
                a3 = fmaf(bf2f((unsigned short)h8[3]), wa.w, a3);
                a0 = fmaf(bf2f((unsigned short)h8[4]), wb.x, a0);
                a1 = fmaf(bf2f((unsigned short)h8[5]), wb.y, a1);
                a2 = fmaf(bf2f((unsigned short)h8[6]), wb.z, a2);
                a3 = fmaf(bf2f((unsigned short)h8[7]), wb.w, a3);
            }
            float flow = ((a0 + a1) + (a2 + a3)) + bl[c];
            int gp = p0 + pt;
            int cp = gp < N ? gp : N - 1;
            if (M == 0) {
                float val = pc0[cp * 3 + c] + flow;
                Al[pt][c] = val;
                if (gp < N) Aout[gp * 3 + c] = val;
            } else {
                float val = Al[pt][c] - flow;
                Cl[pt][c] = val;
                if (gp < N) Cout[gp * 3 + c] = val;
            }
        }
        barrier_nd();
    }
#undef LW
#undef LH
#undef MM

    // ---- epilogue: grid counts for all 4 clouds (block's own points) ----
    if (tid < BP) {
        int gp = p0 + tid;
        if (gp < N) {
            atomicAdd(&counts[1 * GM3 + cell_of(Al[tid][0], Al[tid][1], Al[tid][2])], 1);
            atomicAdd(&counts[3 * GM3 + cell_of(Cl[tid][0], Cl[tid][1], Cl[tid][2])], 1);
            atomicAdd(&counts[0 * GM3 + cell_of(pc1[gp * 3 + 0], pc1[gp * 3 + 1], pc1[gp * 3 + 2])], 1);
            atomicAdd(&counts[2 * GM3 + cell_of(pc0[gp * 3 + 0], pc0[gp * 3 + 1], pc0[gp * 3 + 2])], 1);
        }
    }
}

// ---------------- grid build ----------------
__device__ inline const float* cloud_ptr(int g, const float* g0, const float* g1,
                                         const float* g2, const float* g3)
{
    return g == 0 ? g0 : (g == 1 ? g1 : (g == 2 ? g2 : g3));
}

__global__ __launch_bounds__(256) void scan1(
    const int* __restrict__ counts, int* __restrict__ offs, int* __restrict__ bsum)
{
    int tid = threadIdx.x;
    int i = blockIdx.x * 256 + tid;
    int v = counts[i];
    __shared__ int s[256];
    s[tid] = v;
    __syncthreads();
#pragma unroll
    for (int off = 1; off < 256; off <<= 1) {
        int t = (tid >= off) ? s[tid - off] : 0;
        __syncthreads();
        s[tid] += t;
        __syncthreads();
    }
    offs[i] = s[tid] - v;           // exclusive
    if (tid == 255) bsum[blockIdx.x] = s[255];
}

// scan2+scan3 fused: per-block segment prefix of bsum (SCAN_BLKS=128 <= 256),
// add to offs, re-zero counts (cursors for grid_fill)
__global__ __launch_bounds__(256) void scan23(
    int* __restrict__ offs, const int* __restrict__ bsum, int* __restrict__ counts)
{
    int seg = blockIdx.x / SCAN_BLKS;
    int pos = blockIdx.x - seg * SCAN_BLKS;
    const int* bs = bsum + seg * SCAN_BLKS;
    int t = threadIdx.x;
    int v = (t < pos) ? bs[t] : 0;
    __shared__ int red[4];
#pragma unroll
    for (int o = 32; o > 0; o >>= 1) v += __shfl_down(v, o, 64);
    if ((t & 63) == 0) red[t >> 6] = v;
    __syncthreads();
    int prefix = red[0] + red[1] + red[2] + red[3];
    int i = blockIdx.x * 256 + t;
    offs[i] += prefix;
    counts[i] = 0;
}

__global__ __launch_bounds__(256) void grid_fill(
    const float* __restrict__ B, const float* __restrict__ A,
    const float* __restrict__ D, const float* __restrict__ C,
    const int* __restrict__ offs, int* __restrict__ counts,
    float4* __restrict__ pts, int n)
{
    int g = blockIdx.y;
    const float* P = cloud_ptr(g, B, A, D, C);
    int i = blockIdx.x * 256 + threadIdx.x;
    if (i < n) {
        float x = P[i * 3 + 0], y = P[i * 3 + 1], z = P[i * 3 + 2];
        int c = g * GM3 + cell_of(x, y, z);
        int slot = offs[c] + atomicAdd(&counts[c], 1);
        pts[(size_t)g * n + slot] = make_float4(x, y, z, 0.f);
    }
}

// ---------------- block sum helper ----------------
__device__ inline float block_sum256(float v)
{
    __shared__ float sws[4];
#pragma unroll
    for (int o = 32; o > 0; o >>= 1) v += __shfl_down(v, o, 64);
    int w = threadIdx.x >> 6;
    if ((threadIdx.x & 63) == 0) sws[w] = v;
    __syncthreads();
    if (threadIdx.x == 0) v = sws[0] + sws[1] + sws[2] + sws[3];
    return v;
}

// 1-D box distance from q to cell index c (cell spans [GLO+c*CELL, GLO+(c+1)*CELL])
__device__ inline float boxd1(float q, int c)
{
    float lo = GLO + c * CELL;
    return fmaxf(fmaxf(lo - q, q - (lo + CELL)), 0.f);
}

// cell-sorted truncated NN search with sphere culling (r10/r13-verified structure):
// 2 threads per query (rows 0-3 / 4-8); fmin via LDS; block sum + fused reduce.
__global__ __launch_bounds__(256) void grid_search(
    const int* __restrict__ offs, const int* __restrict__ counts,
    const float4* __restrict__ pts, float* __restrict__ partials,
    unsigned int* __restrict__ done, float* __restrict__ out, float inv, int n)
{
    const int d = blockIdx.y;
    const float4* Qs = pts + (size_t)(d ^ 1) * n;   // sorted query cloud
    const float4* P  = pts + (size_t)d * n;         // sorted target cloud
    const int* ofs = offs + (size_t)d * GM3;
    const int* cnt = counts + (size_t)d * GM3;

    const int tid = threadIdx.x;
    const int ql = tid & (BQ - 1);
    const int half = tid >> 7;          // 0: rows 0-3, 1: rows 4-8
    const int i = blockIdx.x * BQ + ql;

    float mn = 3.4e38f;
    if (i < n) {
        float4 q = Qs[i];
        int cx = min(max((int)floorf((q.x - GLO) * GINV), 0), GM - 1);
        int cy = min(max((int)floorf((q.y - GLO) * GINV), 0), GM - 1);
        int cz = min(max((int)floorf((q.z - GLO) * GINV), 0), GM - 1);
        int xcl = max(cx - 1, 0), xch = min(cx + 1, GM - 1);
        int r0 = half * 4;

        int o[5], e[5];
#pragma unroll
        for (int r = 0; r < 5; ++r) {
            o[r] = 0; e[r] = 0;
            bool act = half ? true : (r < 4);
            if (act) {
                int rr = r0 + r;                 // 0..3 or 4..8
                int dz = rr / 3, dy = rr - dz * 3;
                int z = cz + dz - 1;
                int y = cy + dy - 1;
                if ((unsigned)z < GM && (unsigned)y < GM) {
                    float dzd = boxd1(q.z, z);
                    float dyd = boxd1(q.y, y);
                    float dyz2 = fmaf(dzd, dzd, dyd * dyd);
                    if (dyz2 < TRUNC_) {
                        float rx = sqrtf(TRUNC_ - dyz2);
                        int xlo = max((int)floorf((q.x - rx - GLO) * GINV), xcl);
                        int xhi = min((int)floorf((q.x + rx - GLO) * GINV), xch);
                        if (xlo <= xhi) {
                            int rowbase = (z * GM + y) * GM;
                            o[r] = ofs[rowbase + xlo];
                            e[r] = ofs[rowbase + xhi] + cnt[rowbase + xhi];
                        }
                    }
                }
            }
        }
#pragma unroll
        for (int r = 0; r < 5; ++r) {
            for (int k = o[r]; k < e[r]; ++k) {
                float4 p = P[k];
                float ddx = q.x - p.x, ddy = q.y - p.y, ddz = q.z - p.z;
                mn = fminf(mn, fmaf(ddx, ddx, fmaf(ddy, ddy, ddz * ddz)));
            }
        }
    }

    __shared__ float m0[BQ];
    if (half == 0) m0[ql] = mn;
    __syncthreads();
    float val = 0.f;
    if (half == 1 && i < n) {
        float m = fminf(mn, m0[ql]);
        val = (m < TRUNC_) ? m : 0.f;
    }
    float bs = block_sum256(val);

    __shared__ int lastflag;
    if (tid == 0) {
        atomicExch(&partials[(size_t)d * gridDim.x + blockIdx.x], bs);
        __threadfence();
        unsigned v = atomicAdd(done, 1u);
        lastflag = (v == (unsigned)(NGRID * gridDim.x - 1)) ? 1 : 0;
    }
    __syncthreads();
    if (lastflag) {
        int NPt = NGRID * gridDim.x;
        float s = 0.f;
        for (int j = tid; j < NPt; j += 256)
            s += atomicAdd(&partials[j], 0.0f);   // device-scope read
        __syncthreads();
        float tot = block_sum256(s);
        if (tid == 0) out[0] = tot * inv;
    }
}

// ---------------- launch ----------------
extern "C" void kernel_launch(void* const* d_in, const int* in_sizes, int n_in,
                              void* d_out, int out_size, void* d_ws, size_t ws_size,
                              hipStream_t stream)
{
    const float* pc0 = (const float*)d_in[0];
    const float* pc1 = (const float*)d_in[1];
    const float* W0  = (const float*)d_in[2];
    const float* b0  = (const float*)d_in[3];
    const float* Wh  = (const float*)d_in[4];
    const float* bh  = (const float*)d_in[5];
    const float* Wl  = (const float*)d_in[6];
    const float* bl  = (const float*)d_in[7];
    const float* W0i = (const float*)d_in[8];
    const float* b0i = (const float*)d_in[9];
    const float* Whi = (const float*)d_in[10];
    const float* bhi = (const float*)d_in[11];
    const float* Wli = (const float*)d_in[12];
    const float* bli = (const float*)d_in[13];
    float* out = (float*)d_out;

    const int N = in_sizes[0] / 3;   // 20000

    // ws layout (byte offsets)
    char* base = (char*)d_ws;
    float*  A        = (float*)(base + 0);               // 240000
    float*  C        = (float*)(base + 240000);          // 240000
    int*    counts   = (int*)  (base + 480000);          // 524288
    int*    offs     = (int*)  (base + 1004288);         // 524288
    int*    bsum     = (int*)  (base + 1528576);         // 4096
    float4* pts      = (float4*)(base + 1532672);        // 1280000
    float*  partials = (float*)(base + 2812672);         // 4096
    unsigned int* done = (unsigned int*)(base + 2816768);// 16
    unsigned short* whp = (unsigned short*)(base + 2816784); // 458752
    float*  wlt      = (float*)(base + 3275536);         // 3072

    const int PB = (N + 255) / 256;        // 79
    const int QB = (N + BQ - 1) / BQ;      // 157 search blocks per direction

    // prep: pack weights (bf16) + WlT + zero counts + zero done-counter
    hipLaunchKernelGGL(prep_kernel, dim3(PACKB + ZCB + 1), dim3(256), 0, stream,
                       Wh, Whi, Wl, Wli, whp, wlt, counts, done);

    int mlpg = (N + BP - 1) / BP;  // 250
    hipLaunchKernelGGL(mlp_fused_kernel, dim3(mlpg), dim3(512), 0, stream,
                       pc0, pc1, W0, b0, W0i, b0i, whp, bh, bhi,
                       wlt, bl, bli, A, C, counts, N);

    // grids: g0=pc1, g1=A, g2=pc0, g3=C (counts already done in mlp epilogue)
    hipLaunchKernelGGL(scan1, dim3(ZB), dim3(256), 0, stream, counts, offs, bsum);
    hipLaunchKernelGGL(scan23, dim3(ZB), dim3(256), 0, stream, offs, bsum, counts);
    hipLaunchKernelGGL(grid_fill, dim3(PB, NGRID), dim3(256), 0, stream,
                       pc1, A, pc0, C, offs, counts, pts, N);

    // sphere-culled cell-sorted truncated NN search + fused final reduce
    hipLaunchKernelGGL(grid_search, dim3(QB, NGRID), dim3(256), 0, stream,
                       offs, counts, pts, partials, done, out,
                       1.0f / (float)N, N);
}